// Round 1
// 168.782 us; speedup vs baseline: 1.0184x; 1.0184x over previous
//
#include <hip/hip_runtime.h>
#include <hip/hip_bf16.h>

// PCILT conv2d: qdq(x,8b) conv qdq(W,8b), 3x3 s1 p1.
// 3-kernel pipeline:
//   K1 absmax_part : per-block |x|,|W| partials (into d_out scratch, no atomics)
//   K2 quant_wx    : every block redundantly folds partials -> sx,sw (L2-hot,
//                    removes the 1-block reduce bubble + a launch), quantizes
//                    its x row -> NHWC int8; blocks 0..287 also quantize W.
//   K3 conv_kernel : one block per (n, oh-pair): stage 4 padded int8 rows to
//                    LDS ONCE (one barrier), two passes of 9-tap
//                    ds_read_b128 + mfma_i32_16x16x64_i8 (exact int math),
//                    pass-0 stores overlap pass-1 MFMAs. 896 blocks co-resident.

typedef __attribute__((ext_vector_type(8))) short short8;
typedef __attribute__((ext_vector_type(4))) int   int4v;    // 16 packed i8 (A/B) or i32 C/D
typedef __attribute__((ext_vector_type(4))) float f32x4;
typedef __attribute__((ext_vector_type(4))) float float4v;
typedef __attribute__((ext_vector_type(8)))  signed char char8;
typedef __attribute__((ext_vector_type(16))) signed char char16;

#define N_IMG 16
#define C_IN 64
#define HW 112
#define O_CH 128
#define WPITCH 576        // bytes per o-row in wt8 (9 taps * 64 c)
#define XPITCH 80         // LDS bytes per ow-row (64 + 16 pad: conflict-light)
#define TP 72             // quant_x LDS pitch (halves)
#define NPART 3136        // absmax partial blocks (3136*256*4 float4 == nx4)

// ---------------- kernel 1: per-block absmax partials (NO atomics) ----------
__global__ __launch_bounds__(256) void absmax_part(const float* __restrict__ x,
                                                   const float* __restrict__ w,
                                                   float* __restrict__ part) {
    const int b = blockIdx.x, tid = threadIdx.x;
    const float4v* x4 = (const float4v*)x;
    const long base = (long)b * 1024 + tid;
    const float4v v0 = x4[base];
    const float4v v1 = x4[base + 256];
    const float4v v2 = x4[base + 512];
    const float4v v3 = x4[base + 768];
    float mx = fmaxf(fmaxf(fmaxf(fabsf(v0.x), fabsf(v0.y)), fmaxf(fabsf(v0.z), fabsf(v0.w))),
                     fmaxf(fmaxf(fabsf(v1.x), fabsf(v1.y)), fmaxf(fabsf(v1.z), fabsf(v1.w))));
    mx = fmaxf(mx, fmaxf(fmaxf(fabsf(v2.x), fabsf(v2.y)), fmaxf(fabsf(v2.z), fabsf(v2.w))));
    mx = fmaxf(mx, fmaxf(fmaxf(fabsf(v3.x), fabsf(v3.y)), fmaxf(fabsf(v3.z), fabsf(v3.w))));
    float mw = 0.f;
    if (b < 72) {   // 72*256 float4 == 73,728 W floats exactly
        const float4v q = ((const float4v*)w)[b * 256 + tid];
        mw = fmaxf(fmaxf(fabsf(q.x), fabsf(q.y)), fmaxf(fabsf(q.z), fabsf(q.w)));
    }
    #pragma unroll
    for (int off = 32; off > 0; off >>= 1) {
        mx = fmaxf(mx, __shfl_down(mx, off));
        mw = fmaxf(mw, __shfl_down(mw, off));
    }
    __shared__ float smx[4], smw[4];
    const int wave = tid >> 6, lane = tid & 63;
    if (lane == 0) { smx[wave] = mx; smw[wave] = mw; }
    __syncthreads();
    if (tid == 0) {
        part[b]         = fmaxf(fmaxf(smx[0], smx[1]), fmaxf(smx[2], smx[3]));
        part[NPART + b] = fmaxf(fmaxf(smw[0], smw[1]), fmaxf(smw[2], smw[3]));
    }
}

// -------- kernel 2: fold partials + quantize W + quantize/transpose x --------
// One block per (n,h). Each block folds the 3136+72 partials itself (12.8 KB,
// L2/L3-hot) -> no single-block reduce kernel, no extra launch gap.
// x path: float4 reads along w, LDS transpose (XOR-swizzled c-octets),
// pack 16 int8 per lane, char16 writes along c.
__global__ __launch_bounds__(256) void quant_wx(const float* __restrict__ x,
                                                const float* __restrict__ w,
                                                const float* __restrict__ part,
                                                unsigned* __restrict__ scal,
                                                signed char* __restrict__ wt8,
                                                signed char* __restrict__ xq8) {
    __shared__ __align__(16) short tile[HW * TP];   // quantized ints as short, 16,128 B
    __shared__ float smx[4], smw[4];
    const int tid = threadIdx.x;
    const int wave = tid >> 6, lane = tid & 63;

    // ---- fold partials (redundant per block; reads are cache-hot) ----
    float mx = 0.f, mw = 0.f;
    #pragma unroll
    for (int i = 0; i < 13; ++i) {                  // 13*256 >= 3136
        const int idx = i * 256 + tid;
        if (idx < NPART) mx = fmaxf(mx, part[idx]);
    }
    if (tid < 72) mw = part[NPART + tid];
    #pragma unroll
    for (int off = 32; off > 0; off >>= 1) {
        mx = fmaxf(mx, __shfl_down(mx, off));
        mw = fmaxf(mw, __shfl_down(mw, off));
    }
    if (lane == 0) { smx[wave] = mx; smw[wave] = mw; }
    __syncthreads();
    const float xm = fmaxf(fmaxf(smx[0], smx[1]), fmaxf(smx[2], smx[3]));
    const float wm = fmaxf(fmaxf(smw[0], smw[1]), fmaxf(smw[2], smw[3]));
    const float sx = fmaxf(xm * (1.f / 127.f), 1e-8f);
    const float sw = fmaxf(wm * (1.f / 127.f), 1e-8f);
    if (blockIdx.x == 0 && tid == 0) {              // publish for conv epilogue
        scal[0] = __float_as_uint(xm);
        scal[1] = __float_as_uint(wm);
    }

    // ---- W quant (blocks 0..287 cover 288*256 == 73,728 == O*C*9 exactly) ----
    if (blockIdx.x < 288) {
        const int idx = blockIdx.x * 256 + tid;
        const int kw = idx % 3;
        int t = idx / 3;
        const int kh = t % 3;
        t /= 3;
        const int c = t % C_IN;
        const int o = t / C_IN;
        float v = rintf(w[idx] / sw);
        v = fminf(fmaxf(v, -127.f), 127.f);
        wt8[o * WPITCH + (kh * 3 + kw) * C_IN + c] = (signed char)(int)v;
    }

    // ---- x quant + transpose for this (n,h) row ----
    const int n = blockIdx.x / HW, h = blockIdx.x % HW;
    const float inv_sx = 1.f / sx;
    #pragma unroll
    for (int i = 0; i < 7; ++i) {                   // 7*256 = 1792 = 64c * 28 w-quads
        const int l = i * 256 + tid;
        const int c = l / 28, w4 = l - c * 28;
        const float4v v = *(const float4v*)(x + ((long)(n * C_IN + c) * HW + h) * HW + w4 * 4);
        float q[4];
        q[0] = fminf(fmaxf(rintf(v.x * inv_sx), -127.f), 127.f);
        q[1] = fminf(fmaxf(rintf(v.y * inv_sx), -127.f), 127.f);
        q[2] = fminf(fmaxf(rintf(v.z * inv_sx), -127.f), 127.f);
        q[3] = fminf(fmaxf(rintf(v.w * inv_sx), -127.f), 127.f);
        const int osw = ((c >> 3) ^ (w4 & 7)) * 8 + (c & 7);   // swizzled c position
        #pragma unroll
        for (int j = 0; j < 4; ++j)
            tile[(w4 * 4 + j) * TP + osw] = (short)q[j];
    }
    __syncthreads();
    const int g = tid & 3, wi = tid >> 2;           // 4 c-16-groups x 64 w-slots
    signed char* dst = xq8 + (long)(n * HW + h) * HW * C_IN;
    #pragma unroll
    for (int j = 0; j < 2; ++j) {
        const int ww = j * 64 + wi;
        if (ww < HW) {
            const int sw2 = (ww >> 2) & 7;
            const short8 s0 = *(const short8*)(tile + ww * TP + ((2 * g) ^ sw2) * 8);
            const short8 s1 = *(const short8*)(tile + ww * TP + ((2 * g + 1) ^ sw2) * 8);
            const char8 c0 = __builtin_convertvector(s0, char8);
            const char8 c1 = __builtin_convertvector(s1, char8);
            const char16 cc = __builtin_shufflevector(c0, c1,
                0, 1, 2, 3, 4, 5, 6, 7, 8, 9, 10, 11, 12, 13, 14, 15);
            *(char16*)(dst + ww * C_IN + g * 16) = cc;
        }
    }
}

// ---------------- kernel 3: conv — 2 output rows per block ----------------
// Stage 4 input rows (oh0-1..oh0+2) once; two 9-tap MFMA passes share them.
// 896 blocks (8*112, XCD-bijective swizzle) => all blocks co-resident at
// 4 blocks/CU; pass-0 epilogue stores hide under pass-1 MFMAs.
__global__ __launch_bounds__(256, 4) void conv_kernel(const signed char* __restrict__ xq8,
                                                      const signed char* __restrict__ wt8,
                                                      const unsigned* __restrict__ scal,
                                                      float* __restrict__ out) {
    __shared__ __align__(16) signed char xs[4 * 114 * XPITCH];   // 36,480 B
    const int tid = threadIdx.x;
    const int wave = tid >> 6, lane = tid & 63;
    const int quad = lane >> 4, l16 = lane & 15;
    // XCD swizzle: 896 = 8 * 112 exactly (bijective)
    const int lin = (blockIdx.x & 7) * 112 + (blockIdx.x >> 3);
    const int n = lin / 56, oh0 = (lin % 56) * 2;

    // ---- zero border columns (ow_lds = 0, 113): 4 rows x 2 cols x 4 chunks
    if (tid < 32) {
        const int r = tid >> 3, col = (tid >> 2) & 1, c16 = tid & 3;
        *(int4v*)(xs + (r * 114 + col * 113) * XPITCH + c16 * 16) = (int4v)0;
    }
    // ---- stage 4 rows (ih = oh0-1 .. oh0+2): 1792 chunks = 7*256 exactly ----
    #pragma unroll
    for (int it = 0; it < 7; ++it) {
        const int gph = it * 256 + tid;             // 4 rows * 112 ow * 4 c16
        const int r = gph / 448, rem = gph - r * 448;
        const int ow = rem >> 2, c16 = rem & 3;
        const int ih = oh0 - 1 + r;
        int4v v = (int4v)0;
        if ((unsigned)ih < (unsigned)HW)
            v = *(const int4v*)(xq8 + ((long)(n * HW + ih) * HW + ow) * C_IN + c16 * 16);
        *(int4v*)(xs + (r * 114 + ow + 1) * XPITCH + c16 * 16) = v;
    }

    // B-fragment pointers: wave owns channels [wave*32, wave*32+32)
    const signed char* wrow0 = wt8 + (wave * 32 + l16) * WPITCH + quad * 16;
    const signed char* wrow1 = wrow0 + 16 * WPITCH;
    const float s = fmaxf(__uint_as_float(scal[0]) * (1.f / 127.f), 1e-8f) *
                    fmaxf(__uint_as_float(scal[1]) * (1.f / 127.f), 1e-8f);

    __syncthreads();

    #pragma unroll
    for (int p = 0; p < 2; ++p) {
        int4v acc[7][2];
        #pragma unroll
        for (int mt = 0; mt < 7; ++mt) { acc[mt][0] = (int4v)0; acc[mt][1] = (int4v)0; }

        int4v bcur0 = *(const int4v*)(wrow0);       // L1/L2-hot after pass 0
        int4v bcur1 = *(const int4v*)(wrow1);
        int4v bnxt0, bnxt1;

        #pragma unroll
        for (int tap = 0; tap < 9; ++tap) {
            if (tap < 8) {                          // prefetch next tap's B frags
                bnxt0 = *(const int4v*)(wrow0 + (tap + 1) * C_IN);
                bnxt1 = *(const int4v*)(wrow1 + (tap + 1) * C_IN);
            }
            const signed char* rowb = xs + ((p + tap / 3) * 114 + (tap % 3) + l16) * XPITCH + quad * 16;
            #pragma unroll
            for (int mt = 0; mt < 7; ++mt) {
                const int4v afr = *(const int4v*)(rowb + mt * (16 * XPITCH));
                acc[mt][0] = __builtin_amdgcn_mfma_i32_16x16x64_i8(afr, bcur0, acc[mt][0], 0, 0, 0);
                acc[mt][1] = __builtin_amdgcn_mfma_i32_16x16x64_i8(afr, bcur1, acc[mt][1], 0, 0, 0);
            }
            bcur0 = bnxt0;
            bcur1 = bnxt1;
        }

        // ---- epilogue: dequant + store row oh0+p (4 consecutive ow per lane)
        const int oh = oh0 + p;
        #pragma unroll
        for (int mt = 0; mt < 7; ++mt) {
            #pragma unroll
            for (int ot = 0; ot < 2; ++ot) {
                const int o = wave * 32 + ot * 16 + l16;     // D col = lane&15
                const int mrow = mt * 16 + quad * 4;         // D row = quad*4 + reg
                const f32x4 v = __builtin_convertvector(acc[mt][ot], f32x4) * s;
                *(f32x4*)(out + (((long)(n * O_CH + o) * HW + oh) * HW + mrow)) = v;
            }
        }
    }
}

extern "C" void kernel_launch(void* const* d_in, const int* in_sizes, int n_in,
                              void* d_out, int out_size, void* d_ws, size_t ws_size,
                              hipStream_t stream) {
    const float* x = (const float*)d_in[0];
    const float* W = (const float*)d_in[1];
    float* out = (float*)d_out;

    unsigned* scal = (unsigned*)d_ws;                                    // 8 B
    signed char* wt8 = (signed char*)((char*)d_ws + 1024);               // 73,728 B
    signed char* xq8 = (signed char*)((char*)d_ws + 76800);              // 12,845,056 B
    // partials live in d_out scratch: written by K1, read by K2, overwritten
    // by K3 (stream-ordered, no alias race with xq8 writers).
    float* part = (float*)out;                                           // 2*NPART floats

    hipLaunchKernelGGL(absmax_part, dim3(NPART), dim3(256), 0, stream, x, W, part);
    hipLaunchKernelGGL(quant_wx, dim3(N_IMG * HW), dim3(256), 0, stream,
                       x, W, part, scal, wt8, xq8);
    hipLaunchKernelGGL(conv_kernel, dim3(896), dim3(256), 0, stream, xq8, wt8, scal, out);
}